// Round 2
// baseline (504.549 us; speedup 1.0000x reference)
//
#include <hip/hip_runtime.h>

typedef unsigned short u16;
typedef __attribute__((ext_vector_type(8))) _Float16 hfrag8;  // 8 f16 = 4 VGPRs (MFMA A/B frag)
typedef __attribute__((ext_vector_type(4))) float f32x4;      // MFMA C/D frag

__device__ __forceinline__ float bu2f(u16 u) { return __uint_as_float(((unsigned)u) << 16); }
__device__ __forceinline__ u16 f2bu(float f) {
    unsigned x = __float_as_uint(f);
    return (u16)((x + 0x7fffu + ((x >> 16) & 1u)) >> 16);   // RNE f32->bf16
}
__device__ __forceinline__ u16 f2hu(float f) {              // f32 -> f16 bit pattern
    _Float16 h = (_Float16)f;
    return __builtin_bit_cast(u16, h);
}
__device__ __forceinline__ float ldf(const void* p, int i, bool f32) {
    return f32 ? ((const float*)p)[i] : bu2f(((const u16*)p)[i]);
}
__device__ __forceinline__ float siluf(float x) { return x / (1.0f + __expf(-x)); }

// ---------------------------------------------------------------------------
// A0: dtype detector. Samples even-indexed u16s of node_features.
//   bf16 data: values ~N(0,1), exponent field in ~[112,130], never 0/extreme.
//   f32 data : even u16 = mantissa-low bits = uniform -> ~46% extreme exps.
// ---------------------------------------------------------------------------
__global__ void detect_dtype(const void* nf, int* flag)
{
    const int lane = threadIdx.x;
    const u16* p = (const u16*)nf;
    int ext = 0;
    for (int s = 0; s < 4; s++) {
        u16 v = p[(lane * 4 + s) * 2];
        int e = (v >> 7) & 0xFF;
        ext += (e >= 140 || e == 0) ? 1 : 0;
    }
#pragma unroll
    for (int d = 1; d < 64; d <<= 1) ext += __shfl_xor(ext, d);
    if (lane == 0) flag[0] = (ext > 32) ? 1 : 0;   // 1 = float32, 0 = bf16
}

// ---------------------------------------------------------------------------
// A1: per-node precompute.
//   cbar[b,i,:]  = mean_a coords[b,i,a,:]
//   pi2[b,i,n]   = fi@We1[0:128] + cbar_i@We1[384:387] + be1[n]
//   qd [b,j,n]   = fj@We1[128:256] - cbar_j@We1[384:387]
// edge layer-1 preact = pi2[i] + qd[j] + T[rel(i,j)]
// ---------------------------------------------------------------------------
__global__ __launch_bounds__(256) void precompute_rows(
    const void* __restrict__ coords, const void* __restrict__ nf,
    const void* __restrict__ We1, const void* __restrict__ be1,
    const int* __restrict__ flag,
    float* __restrict__ cbar, float* __restrict__ pi2, float* __restrict__ qd)
{
    const bool f32 = flag[0] != 0;
    const int t = threadIdx.x;
    const int row0 = blockIdx.x * 4;           // 4 (b,i) rows per block
    __shared__ float nf_l[4][128];
    __shared__ float ctmp[4][12];
    __shared__ float cb_l[4][3];
    for (int idx = t; idx < 512; idx += 256) {
        int r = idx >> 7, k = idx & 127;
        nf_l[r][k] = ldf(nf, (row0 + r) * 128 + k, f32);
    }
    if (t < 48) ctmp[t / 12][t % 12] = ldf(coords, row0 * 12 + t, f32);
    __syncthreads();
    if (t < 12) {
        int r = t / 3, x = t % 3;
        float m = 0.25f * (ctmp[r][x] + ctmp[r][3 + x] + ctmp[r][6 + x] + ctmp[r][9 + x]);
        cb_l[r][x] = m;
        cbar[(row0 + r) * 3 + x] = m;
    }
    __syncthreads();
    const int n = t;
    float accP[4] = {0.f, 0.f, 0.f, 0.f}, accQ[4] = {0.f, 0.f, 0.f, 0.f};
    for (int k = 0; k < 128; k++) {
        float w1 = ldf(We1, k * 256 + n, f32);
        float w2 = ldf(We1, (128 + k) * 256 + n, f32);
#pragma unroll
        for (int r = 0; r < 4; r++) {
            accP[r] += nf_l[r][k] * w1;
            accQ[r] += nf_l[r][k] * w2;
        }
    }
    float wx = ldf(We1, 384 * 256 + n, f32);
    float wy = ldf(We1, 385 * 256 + n, f32);
    float wz = ldf(We1, 386 * 256 + n, f32);
    float b1 = ldf(be1, n, f32);
#pragma unroll
    for (int r = 0; r < 4; r++) {
        float d = cb_l[r][0] * wx + cb_l[r][1] * wy + cb_l[r][2] * wz;
        pi2[(row0 + r) * 256 + n] = accP[r] + d + b1;
        qd[(row0 + r) * 256 + n]  = accQ[r] - d;
    }
}

// ---------------------------------------------------------------------------
// A2: T[d+255][n] = sinusoidal_pe(d) @ We1[256:384]   for d in [-255,255]
// ---------------------------------------------------------------------------
__global__ __launch_bounds__(256) void precompute_T(
    const void* __restrict__ We1, const int* __restrict__ flag,
    float* __restrict__ Ttab)
{
    const bool f32 = flag[0] != 0;
    const int t = threadIdx.x;
    const float d = (float)((int)blockIdx.x - 255);
    __shared__ float pe[128];
    if (t < 64) {
        float ang = d * 3.14159265358979323846f * exp2f(-(float)t * 0.125f);
        pe[t] = sinf(ang);
        pe[64 + t] = cosf(ang);
    }
    __syncthreads();
    float acc = 0.f;
    for (int k = 0; k < 128; k++) acc += pe[k] * ldf(We1, (256 + k) * 256 + t, f32);
    Ttab[blockIdx.x * 256 + t] = acc;
}

// ---------------------------------------------------------------------------
// A3: transpose We2, Wc1 (256x256) -> n-major, k-contiguous, stored as f16
// ---------------------------------------------------------------------------
__global__ __launch_bounds__(256) void transpose_w(
    const void* __restrict__ We2, const void* __restrict__ Wc1,
    const int* __restrict__ flag,
    u16* __restrict__ We2T, u16* __restrict__ Wc1T)
{
    const bool f32 = flag[0] != 0;
    __shared__ u16 tile[32][33];
    int mat = blockIdx.x >> 6;
    int tb = blockIdx.x & 63;
    int bx = tb & 7, by = tb >> 3;
    const void* src = mat ? Wc1 : We2;
    u16* dst = mat ? Wc1T : We2T;
    int tx = threadIdx.x & 31, ty = threadIdx.x >> 5;
#pragma unroll
    for (int p = 0; p < 4; p++) {
        int r = by * 32 + ty + p * 8;
        tile[ty + p * 8][tx] = f2hu(ldf(src, r * 256 + bx * 32 + tx, f32));
    }
    __syncthreads();
#pragma unroll
    for (int p = 0; p < 4; p++) {
        int r = bx * 32 + ty + p * 8;
        dst[r * 256 + by * 32 + tx] = tile[tx][ty + p * 8];
    }
}

// ---------------------------------------------------------------------------
// B: fused edge kernel. One WG per (b,i); loops j in 4 chunks of 64.
//   h1  = silu(pi2[i] + qd[j] + T[rel])          (no GEMM - table trick)
//   msg = silu(h1 @ We2 + be2)                   (f16 MFMA, 64x256x256)
//   agg[i] += sum_j msg ;  cu = silu(msg@Wc1+bc1).Wc2+bc2 (MFMA + lane dot)
//   coordacc += {sum cu, sum cu*cbar_j}
// ---------------------------------------------------------------------------
__global__ __launch_bounds__(256, 2) void edge_kernel(
    const int* __restrict__ resid,
    const float* __restrict__ pi2, const float* __restrict__ qd,
    const float* __restrict__ Ttab, const float* __restrict__ cbar,
    const u16* __restrict__ We2T, const u16* __restrict__ Wc1T,
    const void* __restrict__ be2, const void* __restrict__ bc1,
    const void* __restrict__ Wc2, const void* __restrict__ bc2,
    const int* __restrict__ flag,
    float* __restrict__ agg_out, float* __restrict__ cupd_out)
{
    const bool f32 = flag[0] != 0;
    const int wg = blockIdx.x;            // b*256 + i
    const int b = wg >> 8;
    const int t = threadIdx.x;
    const int lane = t & 63, w = t >> 6;  // 4 waves; wave w owns cols [64w,64w+64)
    const int c = lane & 15, q = lane >> 4;

    __shared__ __align__(16) u16 h1[64][264];   // f16 bits, row pad +8
    __shared__ __align__(16) u16 msg[64][264];
    __shared__ float pi2_l[256], be2_l[256], bc1_l[256], wc2_l[256], agg_l[256];
    __shared__ int relidx[256];
    __shared__ float cupart[4][64];
    __shared__ float cacc[4];
    __shared__ float cbi[3];

    int ri = resid[(b << 8) + (wg & 255)];
    relidx[t] = ri - resid[(b << 8) + t] + 255;
    pi2_l[t] = pi2[wg * 256 + t];
    be2_l[t] = ldf(be2, t, f32);
    bc1_l[t] = ldf(bc1, t, f32);
    wc2_l[t] = ldf(Wc2, t, f32);
    agg_l[t] = 0.f;
    if (t < 4) cacc[t] = 0.f;
    if (t < 3) cbi[t] = cbar[wg * 3 + t];
    const float bc2v = ldf(bc2, 0, f32);
    __syncthreads();

    for (int jc = 0; jc < 4; jc++) {
        const int j0 = jc << 6;
        // ---- phase 1: build h1 (silu of table sum), f16 into LDS ----
        {
            const int k = (t & 127) << 1;
            const int jh = t >> 7;
            const float p0 = pi2_l[k], p1 = pi2_l[k + 1];
            for (int jj = jh * 32; jj < jh * 32 + 32; jj++) {
                const int j = j0 + jj;
                const float2 qv = *(const float2*)(qd + ((b << 8) + j) * 256 + k);
                const float2 tv = *(const float2*)(Ttab + relidx[j] * 256 + k);
                float v0 = siluf(p0 + qv.x + tv.x);
                float v1 = siluf(p1 + qv.y + tv.y);
                *(unsigned*)&h1[jj][k] = (unsigned)f2hu(v0) | ((unsigned)f2hu(v1) << 16);
            }
        }
        __syncthreads();

        // ---- phase 2: msg = silu(h1 @ We2 + be2); agg accumulate ----
        f32x4 acc[4][4];
        const f32x4 zf = {0.f, 0.f, 0.f, 0.f};
#pragma unroll
        for (int m = 0; m < 4; m++)
#pragma unroll
            for (int n = 0; n < 4; n++) acc[m][n] = zf;
#pragma unroll
        for (int ks = 0; ks < 8; ks++) {
            const int kb = ks * 32 + q * 8;
            hfrag8 a[4], bb[4];
#pragma unroll
            for (int m = 0; m < 4; m++) a[m] = *(const hfrag8*)&h1[m * 16 + c][kb];
#pragma unroll
            for (int n = 0; n < 4; n++)
                bb[n] = *(const hfrag8*)(We2T + (w * 64 + n * 16 + c) * 256 + kb);
#pragma unroll
            for (int m = 0; m < 4; m++)
#pragma unroll
                for (int n = 0; n < 4; n++)
                    acc[m][n] = __builtin_amdgcn_mfma_f32_16x16x32_f16(a[m], bb[n], acc[m][n], 0, 0, 0);
        }
#pragma unroll
        for (int n = 0; n < 4; n++) {
            const int col = w * 64 + n * 16 + c;
            const float bias = be2_l[col];
            float part = 0.f;
#pragma unroll
            for (int m = 0; m < 4; m++) {
#pragma unroll
                for (int r = 0; r < 4; r++) {
                    float s = siluf(acc[m][n][r] + bias);
                    part += s;
                    msg[m * 16 + q * 4 + r][col] = f2hu(s);
                }
            }
            part += __shfl_xor(part, 16);
            part += __shfl_xor(part, 32);
            if (q == 0) agg_l[col] += part;   // waves own disjoint cols
        }
        __syncthreads();

        // ---- phase 3: cu_h = silu(msg @ Wc1 + bc1); cu = cu_h . Wc2 + bc2 ----
#pragma unroll
        for (int m = 0; m < 4; m++)
#pragma unroll
            for (int n = 0; n < 4; n++) acc[m][n] = zf;
#pragma unroll
        for (int ks = 0; ks < 8; ks++) {
            const int kb = ks * 32 + q * 8;
            hfrag8 a[4], bb[4];
#pragma unroll
            for (int m = 0; m < 4; m++) a[m] = *(const hfrag8*)&msg[m * 16 + c][kb];
#pragma unroll
            for (int n = 0; n < 4; n++)
                bb[n] = *(const hfrag8*)(Wc1T + (w * 64 + n * 16 + c) * 256 + kb);
#pragma unroll
            for (int m = 0; m < 4; m++)
#pragma unroll
                for (int n = 0; n < 4; n++)
                    acc[m][n] = __builtin_amdgcn_mfma_f32_16x16x32_f16(a[m], bb[n], acc[m][n], 0, 0, 0);
        }
        float dotv[4][4];
#pragma unroll
        for (int m = 0; m < 4; m++)
#pragma unroll
            for (int r = 0; r < 4; r++) dotv[m][r] = 0.f;
#pragma unroll
        for (int n = 0; n < 4; n++) {
            const int col = w * 64 + n * 16 + c;
            const float bias = bc1_l[col];
            const float wv = wc2_l[col];
#pragma unroll
            for (int m = 0; m < 4; m++)
#pragma unroll
                for (int r = 0; r < 4; r++)
                    dotv[m][r] += siluf(acc[m][n][r] + bias) * wv;
        }
#pragma unroll
        for (int m = 0; m < 4; m++) {
#pragma unroll
            for (int r = 0; r < 4; r++) {
                float v = dotv[m][r];
                v += __shfl_xor(v, 1);
                v += __shfl_xor(v, 2);
                v += __shfl_xor(v, 4);
                v += __shfl_xor(v, 8);
                if (c == 0) cupart[w][m * 16 + q * 4 + r] = v;  // wave-partial row dot
            }
        }
        __syncthreads();
        if (w == 0) {                                   // cross-wave cu + coord accum
            const int j = j0 + lane;
            float cu = cupart[0][lane] + cupart[1][lane] + cupart[2][lane] + cupart[3][lane] + bc2v;
            const float cx = cbar[((b << 8) + j) * 3 + 0];
            const float cy = cbar[((b << 8) + j) * 3 + 1];
            const float cz = cbar[((b << 8) + j) * 3 + 2];
            float s0 = cu, s1 = cu * cx, s2 = cu * cy, s3 = cu * cz;
#pragma unroll
            for (int d = 1; d < 64; d <<= 1) {
                s0 += __shfl_xor(s0, d);
                s1 += __shfl_xor(s1, d);
                s2 += __shfl_xor(s2, d);
                s3 += __shfl_xor(s3, d);
            }
            if (lane == 0) { cacc[0] += s0; cacc[1] += s1; cacc[2] += s2; cacc[3] += s3; }
        }
        __syncthreads();
    }
    agg_out[wg * 256 + t] = agg_l[t];
    if (t == 0) {
        // coord_upd = (sum cu)*cbar_i - sum(cu*cbar_j)
        cupd_out[wg * 3 + 0] = cacc[0] * cbi[0] - cacc[1];
        cupd_out[wg * 3 + 1] = cacc[0] * cbi[1] - cacc[2];
        cupd_out[wg * 3 + 2] = cacc[0] * cbi[2] - cacc[3];
    }
}

// ---------------------------------------------------------------------------
// C: node MLP + LayerNorm. 8 rows per block. Writes h into d_out[12288..].
// ---------------------------------------------------------------------------
__global__ __launch_bounds__(256) void node_kernel(
    const void* __restrict__ nf, const float* __restrict__ agg,
    const void* __restrict__ Wn1, const void* __restrict__ bn1,
    const void* __restrict__ Wn2, const void* __restrict__ bn2,
    const void* __restrict__ gamma, const void* __restrict__ beta,
    const int* __restrict__ flag, void* __restrict__ d_out)
{
    const bool f32 = flag[0] != 0;
    const int t = threadIdx.x;
    const int row0 = blockIdx.x * 8;
    __shared__ float x_l[8][384];
    __shared__ float hs[8][256];
    __shared__ float ho[8][128];
    for (int idx = t; idx < 8 * 384; idx += 256) {
        int r = idx / 384, k = idx % 384;
        x_l[r][k] = (k < 128) ? ldf(nf, (row0 + r) * 128 + k, f32)
                              : agg[(row0 + r) * 256 + (k - 128)];
    }
    __syncthreads();
    {
        float a1[8] = {0.f, 0.f, 0.f, 0.f, 0.f, 0.f, 0.f, 0.f};
        for (int k = 0; k < 384; k++) {
            float wv = ldf(Wn1, k * 256 + t, f32);
#pragma unroll
            for (int r = 0; r < 8; r++) a1[r] += x_l[r][k] * wv;
        }
        float b1 = ldf(bn1, t, f32);
#pragma unroll
        for (int r = 0; r < 8; r++) hs[r][t] = siluf(a1[r] + b1);
    }
    __syncthreads();
    {
        int cc = t & 127, rg = (t >> 7) * 4;
        float a2[4] = {0.f, 0.f, 0.f, 0.f};
        for (int k = 0; k < 256; k++) {
            float wv = ldf(Wn2, k * 128 + cc, f32);
#pragma unroll
            for (int r = 0; r < 4; r++) a2[r] += hs[rg + r][k] * wv;
        }
        float b2 = ldf(bn2, cc, f32);
#pragma unroll
        for (int r = 0; r < 4; r++) ho[rg + r][cc] = a2[r] + b2;
    }
    __syncthreads();
    {
        int row = t >> 5, s = t & 31;
        float sm = 0.f, sq = 0.f;
#pragma unroll
        for (int u = 0; u < 4; u++) {
            float v = ho[row][s + 32 * u];
            sm += v; sq += v * v;
        }
#pragma unroll
        for (int d = 1; d < 32; d <<= 1) {
            sm += __shfl_xor(sm, d);
            sq += __shfl_xor(sq, d);
        }
        float mu = sm * (1.f / 128.f);
        float var = sq * (1.f / 128.f) - mu * mu;
        float inv = rsqrtf(var + 1e-5f);
#pragma unroll
        for (int u = 0; u < 4; u++) {
            int cc = s + 32 * u;
            float y = (ho[row][cc] - mu) * inv;
            float outv = y * ldf(gamma, cc, f32) + ldf(beta, cc, f32);
            int oi = 12288 + (row0 + row) * 128 + cc;
            if (f32) ((float*)d_out)[oi] = outv;
            else     ((u16*)d_out)[oi] = f2bu(outv);
        }
    }
}

// ---------------------------------------------------------------------------
// D: updated_coords = coords + coord_upd * atom_mask  -> d_out[0..12288)
// ---------------------------------------------------------------------------
__global__ __launch_bounds__(256) void coords_kernel(
    const void* __restrict__ coords, const void* __restrict__ mask,
    const float* __restrict__ cupd, const int* __restrict__ flag,
    void* __restrict__ d_out)
{
    const bool f32 = flag[0] != 0;
    int idx = blockIdx.x * 256 + threadIdx.x;
    if (idx >= 4 * 256 * 4 * 3) return;
    int x = idx % 3;
    int a = (idx / 3) & 3;
    int node = idx / 12;
    float v = ldf(coords, idx, f32) + cupd[node * 3 + x] * ldf(mask, node * 4 + a, f32);
    if (f32) ((float*)d_out)[idx] = v;
    else     ((u16*)d_out)[idx] = f2bu(v);
}

extern "C" void kernel_launch(void* const* d_in, const int* in_sizes, int n_in,
                              void* d_out, int out_size, void* d_ws, size_t ws_size,
                              hipStream_t stream)
{
    const void* coords = d_in[0];
    const void* nf     = d_in[1];
    const void* mask   = d_in[2];
    const int* resid   = (const int*)d_in[3];
    const void* We1 = d_in[4];
    const void* be1 = d_in[5];
    const void* We2 = d_in[6];
    const void* be2 = d_in[7];
    const void* Wn1 = d_in[8];
    const void* bn1 = d_in[9];
    const void* Wn2 = d_in[10];
    const void* bn2 = d_in[11];
    const void* gamma = d_in[12];
    const void* beta  = d_in[13];
    const void* Wc1 = d_in[14];
    const void* bc1 = d_in[15];
    const void* Wc2 = d_in[16];
    const void* bc2 = d_in[17];

    // workspace layout: [flag(16 floats pad)][f32 arrays][f16 weight arrays] ~3.96 MB
    int* flag  = (int*)d_ws;
    float* f   = (float*)d_ws + 16;
    float* cbar = f;                 // 1024*3
    float* pi2  = cbar + 3072;       // 1024*256
    float* qd   = pi2 + 262144;      // 1024*256
    float* Ttab = qd + 262144;       // 511*256
    float* agg  = Ttab + 130816;     // 1024*256
    float* cupd = agg + 262144;      // 1024*3
    u16* We2T = (u16*)(cupd + 3072); // 256*256 f16
    u16* Wc1T = We2T + 65536;        // 256*256 f16

    hipLaunchKernelGGL(detect_dtype, dim3(1), dim3(64), 0, stream, nf, flag);
    hipLaunchKernelGGL(precompute_rows, dim3(256), dim3(256), 0, stream,
                       coords, nf, We1, be1, flag, cbar, pi2, qd);
    hipLaunchKernelGGL(precompute_T, dim3(511), dim3(256), 0, stream, We1, flag, Ttab);
    hipLaunchKernelGGL(transpose_w, dim3(128), dim3(256), 0, stream, We2, Wc1, flag, We2T, Wc1T);
    hipLaunchKernelGGL(edge_kernel, dim3(1024), dim3(256), 0, stream,
                       resid, pi2, qd, Ttab, cbar, We2T, Wc1T, be2, bc1, Wc2, bc2, flag, agg, cupd);
    hipLaunchKernelGGL(node_kernel, dim3(128), dim3(256), 0, stream,
                       nf, agg, Wn1, bn1, Wn2, bn2, gamma, beta, flag, d_out);
    hipLaunchKernelGGL(coords_kernel, dim3(48), dim3(256), 0, stream,
                       coords, mask, cupd, flag, d_out);
}